// Round 2
// baseline (500.973 us; speedup 1.0000x reference)
//
#include <hip/hip_runtime.h>

// Bilinear grid sample, B=8 H=512 W=512 C=32, fp32.
// Mapping: 8 threads per PIXEL-PAIR; thread handles float4 of channels for
// two consecutive pixels.
//  - per-thread: 1x float4 grid load (two pixels' coords), 8 independent
//    128B-line gathers in flight (2x MLP vs 1-pixel version), 2 stores.
//  - gathered img pixel = one aligned 128B line, read by 8 consecutive lanes
//    as coalesced float4s -> full line utilization.
//  - stores: wave writes 2KiB contiguous.
// R1 post-mortem: nt-store was neutral (FETCH 487->479MB, dur ~same) ->
// reverted. Theory now: latency/MLP-bound (VALUBusy 15%, HBM 48%, no pipe
// saturated). This version doubles outstanding gathers per wave.

__global__ __launch_bounds__(256) void Interpolate_86775519248465_kernel(
    const float* __restrict__ img,
    const float* __restrict__ grid,
    float* __restrict__ out)
{
    constexpr int W = 512;
    constexpr int C = 32;
    constexpr float MAXX = 511.0f;   // W-1
    constexpr float MAXY = 511.0f;   // H-1

    const unsigned gid = blockIdx.x * 256u + threadIdx.x;
    const unsigned pp  = gid >> 3;           // pixel-pair index
    const unsigned c   = (gid & 7u) << 2;    // channel start (float4)
    const unsigned pix0 = pp << 1;           // first pixel of the pair

    // grid: [B,H,W,2] flat; two consecutive pixels = 4 consecutive floats.
    const float4 g = *reinterpret_cast<const float4*>(grid + (size_t)pix0 * 2u);

    // ---- pixel 0 coords/weights ----
    const float xA = 0.5f * ((g.x + 1.0f) * MAXX);
    const float yA = 0.5f * ((g.y + 1.0f) * MAXY);
    const int x0A = (int)floorf(xA);
    const int y0A = (int)floorf(yA);
    const int x0cA = min(max(x0A,     0), 511);
    const int x1cA = min(max(x0A + 1, 0), 511);
    const int y0cA = min(max(y0A,     0), 511);
    const int y1cA = min(max(y0A + 1, 0), 511);

    // ---- pixel 1 coords/weights ----
    const float xB = 0.5f * ((g.z + 1.0f) * MAXX);
    const float yB = 0.5f * ((g.w + 1.0f) * MAXY);
    const int x0B = (int)floorf(xB);
    const int y0B = (int)floorf(yB);
    const int x0cB = min(max(x0B,     0), 511);
    const int x1cB = min(max(x0B + 1, 0), 511);
    const int y0cB = min(max(y0B,     0), 511);
    const int y1cB = min(max(y0B + 1, 0), 511);

    // img base: b*H*W*C ; H*W = 2^18. Pairs never straddle a batch boundary.
    const unsigned b = pix0 >> 18;
    const float* __restrict__ ibase = img + ((size_t)b << 18) * (size_t)C;

    // ---- issue all 8 independent gathers ----
    const float4 IaA = *reinterpret_cast<const float4*>(ibase + (unsigned)(y0cA*W + x0cA)*C + c);
    const float4 IbA = *reinterpret_cast<const float4*>(ibase + (unsigned)(y1cA*W + x0cA)*C + c);
    const float4 IcA = *reinterpret_cast<const float4*>(ibase + (unsigned)(y0cA*W + x1cA)*C + c);
    const float4 IdA = *reinterpret_cast<const float4*>(ibase + (unsigned)(y1cA*W + x1cA)*C + c);
    const float4 IaB = *reinterpret_cast<const float4*>(ibase + (unsigned)(y0cB*W + x0cB)*C + c);
    const float4 IbB = *reinterpret_cast<const float4*>(ibase + (unsigned)(y1cB*W + x0cB)*C + c);
    const float4 IcB = *reinterpret_cast<const float4*>(ibase + (unsigned)(y0cB*W + x1cB)*C + c);
    const float4 IdB = *reinterpret_cast<const float4*>(ibase + (unsigned)(y1cB*W + x1cB)*C + c);

    // weights from CLIPPED coords (matches reference exactly)
    const float waA = ((float)x1cA - xA) * ((float)y1cA - yA);
    const float wbA = ((float)x1cA - xA) * (yA - (float)y0cA);
    const float wcA = (xA - (float)x0cA) * ((float)y1cA - yA);
    const float wdA = (xA - (float)x0cA) * (yA - (float)y0cA);

    const float waB = ((float)x1cB - xB) * ((float)y1cB - yB);
    const float wbB = ((float)x1cB - xB) * (yB - (float)y0cB);
    const float wcB = (xB - (float)x0cB) * ((float)y1cB - yB);
    const float wdB = (xB - (float)x0cB) * (yB - (float)y0cB);

    float4 oA;
    oA.x = waA * IaA.x + wbA * IbA.x + wcA * IcA.x + wdA * IdA.x;
    oA.y = waA * IaA.y + wbA * IbA.y + wcA * IcA.y + wdA * IdA.y;
    oA.z = waA * IaA.z + wbA * IbA.z + wcA * IcA.z + wdA * IdA.z;
    oA.w = waA * IaA.w + wbA * IbA.w + wcA * IcA.w + wdA * IdA.w;

    float4 oB;
    oB.x = waB * IaB.x + wbB * IbB.x + wcB * IcB.x + wdB * IdB.x;
    oB.y = waB * IaB.y + wbB * IbB.y + wcB * IcB.y + wdB * IdB.y;
    oB.z = waB * IaB.z + wbB * IbB.z + wcB * IcB.z + wdB * IdB.z;
    oB.w = waB * IaB.w + wbB * IbB.w + wcB * IcB.w + wdB * IdB.w;

    *reinterpret_cast<float4*>(out + (size_t)pix0 * C + c)       = oA;
    *reinterpret_cast<float4*>(out + (size_t)(pix0 + 1) * C + c) = oB;
}

extern "C" void kernel_launch(void* const* d_in, const int* in_sizes, int n_in,
                              void* d_out, int out_size, void* d_ws, size_t ws_size,
                              hipStream_t stream) {
    const float* img  = (const float*)d_in[0];
    const float* grid = (const float*)d_in[1];
    float* out = (float*)d_out;

    // total threads = B*H*W*(C/4)/2 = 8*512*512*4 = 8,388,608
    const unsigned total = 8u * 512u * 512u * 4u;
    const unsigned block = 256u;
    const unsigned nblk = total / block;  // 32768
    Interpolate_86775519248465_kernel<<<nblk, block, 0, stream>>>(img, grid, out);
}